// Round 16
// baseline (259.673 us; speedup 1.0000x reference)
//
#include <hip/hip_runtime.h>
#include <cstdint>
#include <cstddef>

typedef short s8v __attribute__((ext_vector_type(8)));
typedef short s4v __attribute__((ext_vector_type(4)));
typedef float f4v __attribute__((ext_vector_type(4)));

static __device__ __forceinline__ float b2f(short s){
  return __uint_as_float(((uint32_t)(uint16_t)s) << 16);
}
static __device__ __forceinline__ short f2bf(float f){
  uint32_t u = __float_as_uint(f);
  u = (u + 0x7fffu + ((u >> 16) & 1u)) >> 16;
  return (short)(uint16_t)u;
}

// ---- graph prep (fused) ----
__global__ void k_deg(const int* __restrict__ tgt, int* __restrict__ deg, int nE){
  int e = blockIdx.x*blockDim.x + threadIdx.x;
  if(e < nE) atomicAdd(&deg[tgt[e]], 1);
}

#define SCAN_BS 256
__global__ void k_scan1_dinv(const int* __restrict__ deg, int* __restrict__ rowptr,
                             int* __restrict__ blocksum, float* __restrict__ dinv, int nN){
  __shared__ int tmp[SCAN_BS];
  const int t = threadIdx.x;
  const int i = blockIdx.x*SCAN_BS + t;
  int v = (i < nN) ? deg[i] : 0;
  if(i < nN) dinv[i] = rsqrtf((float)v + 1.0f);   // +1 self-loop
  tmp[t] = v; __syncthreads();
  #pragma unroll
  for(int off=1; off<SCAN_BS; off<<=1){
    int x = (t >= off) ? tmp[t-off] : 0;
    __syncthreads();
    tmp[t] += x;
    __syncthreads();
  }
  if(i < nN) rowptr[i] = tmp[t] - v;
  if(t == SCAN_BS-1) blocksum[blockIdx.x] = tmp[t];
}
__global__ void k_scan2_bounds(int* __restrict__ blocksum, int nb,
                               const int* __restrict__ batch, int* __restrict__ gstart,
                               int nN, int nG){
  __shared__ int tmp[1024];
  const int t = threadIdx.x;
  int v = (t < nb) ? blocksum[t] : 0;
  tmp[t] = v; __syncthreads();
  #pragma unroll
  for(int off=1; off<1024; off<<=1){
    int x = (t >= off) ? tmp[t-off] : 0;
    __syncthreads();
    tmp[t] += x;
    __syncthreads();
  }
  if(t < nb) blocksum[t] = tmp[t] - v;
  if(t <= nG){
    int lo = 0, hi = nN;
    while(lo < hi){
      int mid = (lo + hi) >> 1;
      if(batch[mid] < t) lo = mid + 1; else hi = mid;
    }
    gstart[t] = lo;
  }
}
__global__ void k_scan3(int* __restrict__ rowptr, const int* __restrict__ blocksum,
                        int nN, int nE){
  const int i = blockIdx.x*SCAN_BS + threadIdx.x;
  if(i < nN) rowptr[i] += blocksum[blockIdx.x];
  if(i == 0) rowptr[nN] = nE;
}
__global__ void k_fill(const int* __restrict__ src, const int* __restrict__ tgt,
                       const int* __restrict__ rowptr, int* __restrict__ cursor,
                       int* __restrict__ csr_src, float* __restrict__ csr_w,
                       const float* __restrict__ dinv, int nE){
  int e = blockIdx.x*blockDim.x + threadIdx.x;
  if(e >= nE) return;
  int t = tgt[e];
  int s = src[e];
  int pos = rowptr[t] + atomicAdd(&cursor[t], 1);
  csr_src[pos] = s;
  csr_w[pos] = dinv[s] * dinv[t];
}
__global__ void k_transpose_cvt2(const float* __restrict__ W1, short* __restrict__ W1T,
                                 int K1, const float* __restrict__ W2, short* __restrict__ W2T,
                                 int K2, int N){
  int g = blockIdx.x*blockDim.x + threadIdx.x;
  const int t1 = K1*N;
  if(g < t1){
    int n = g / K1, k = g % K1;
    W1T[(size_t)n*K1 + k] = f2bf(W1[(size_t)k*N + n]);
  } else {
    g -= t1;
    if(g >= K2*N) return;
    int n = g / K2, k = g % K2;
    W2T[(size_t)n*K2 + k] = f2bf(W2[(size_t)k*N + n]);
  }
}

// ---- streaming GEMM: REG-staged (T14 issue-early/write-late), NBUF=2 ----
// (round-14 proven config: 128x128 tile, grid (M/128, N/128), 32 KB LDS)
template<bool AF32>
__global__ __launch_bounds__(256) void gemm_stream(const void* __restrict__ Ap,
    const short* __restrict__ Bt, short* __restrict__ C, int M, int N, int K)
{
  __shared__ __align__(16) short As[2][128*32];
  __shared__ __align__(16) short Bs[2][128*32];
  const int tid  = threadIdx.x;
  const int lane = tid & 63;
  const int wv   = tid >> 6;
  const int lr   = lane & 15;
  const int hi   = lane >> 4;
  const int blk_row = blockIdx.x * 128;
  const int blk_col = blockIdx.y * 128;
  const int nkc = K / 32;

  f4v acc[2][8];
  #pragma unroll
  for(int s=0;s<2;s++)
    #pragma unroll
    for(int nf=0;nf<8;nf++){ acc[s][nf][0]=0.f; acc[s][nf][1]=0.f; acc[s][nf][2]=0.f; acc[s][nf][3]=0.f; }

  f4v ar[4];
  s8v ab2[2];
  s8v br[2];

  auto LOAD = [&](int kc){
    if constexpr(AF32){
      #pragma unroll
      for(int j=0;j<4;j++){
        const int lrow = wv*32 + j*8 + (lane>>3);
        int grow = blk_row + lrow; if(grow >= M) grow = M-1;
        ar[j] = *(const f4v*)((const char*)Ap + ((size_t)grow*K + (size_t)kc*32)*4 + ((lane&7)<<4));
      }
    } else {
      #pragma unroll
      for(int j=0;j<2;j++){
        const int lrow = wv*32 + j*16 + (lane>>2);
        int grow = blk_row + lrow; if(grow >= M) grow = M-1;
        ab2[j] = *(const s8v*)((const char*)Ap + ((size_t)grow*K + (size_t)kc*32)*2 + ((lane&3)<<4));
      }
    }
    #pragma unroll
    for(int j=0;j<2;j++){
      const int lrow = wv*32 + j*16 + (lane>>2);
      br[j] = *(const s8v*)((const char*)Bt + ((size_t)(blk_col+lrow)*K + (size_t)kc*32)*2 + ((lane&3)<<4));
    }
  };
  auto WRITE = [&](int buf){
    if constexpr(AF32){
      #pragma unroll
      for(int j=0;j<4;j++){
        const int lrow = wv*32 + j*8 + (lane>>3);
        const int sl = lane & 7;
        const int c = (sl>>1) ^ ((lrow>>1)&3);
        s4v v;
        #pragma unroll
        for(int q=0;q<4;q++) v[q] = f2bf(ar[j][q]);
        *(s4v*)(&As[buf][lrow*32 + c*8 + (sl&1)*4]) = v;
      }
    } else {
      #pragma unroll
      for(int j=0;j<2;j++){
        const int lrow = wv*32 + j*16 + (lane>>2);
        const int c = (lane&3) ^ ((lrow>>1)&3);
        *(s8v*)(&As[buf][lrow*32 + c*8]) = ab2[j];
      }
    }
    #pragma unroll
    for(int j=0;j<2;j++){
      const int lrow = wv*32 + j*16 + (lane>>2);
      const int c = (lane&3) ^ ((lrow>>1)&3);
      *(s8v*)(&Bs[buf][lrow*32 + c*8]) = br[j];
    }
  };

  LOAD(0);
  asm volatile("s_waitcnt vmcnt(0)" ::: "memory");
  WRITE(0);
  if(nkc > 1) LOAD(1);
  asm volatile("s_waitcnt lgkmcnt(0)" ::: "memory");
  __builtin_amdgcn_s_barrier();
  __builtin_amdgcn_sched_barrier(0);

  for(int kc=0; kc<nkc; kc++){
    const char* ab = (const char*)&As[kc&1][0];
    const char* bb = (const char*)&Bs[kc&1][0];

    s8v a[2];
    #pragma unroll
    for(int s=0;s<2;s++){
      const int row = wv*32 + s*16 + lr;
      const int c = hi ^ ((row>>1) & 3);
      a[s] = *(const s8v*)(ab + row*64 + (c<<4));
    }
    #pragma unroll
    for(int nf=0;nf<8;nf++){
      const int brow = nf*16 + lr;
      const int c = hi ^ ((brow>>1) & 3);
      s8v bfr = *(const s8v*)(bb + brow*64 + (c<<4));
      acc[0][nf] = __builtin_amdgcn_mfma_f32_16x16x32_bf16(a[0], bfr, acc[0][nf], 0, 0, 0);
      acc[1][nf] = __builtin_amdgcn_mfma_f32_16x16x32_bf16(a[1], bfr, acc[1][nf], 0, 0, 0);
    }

    if(kc+1 < nkc){
      asm volatile("s_waitcnt vmcnt(0)" ::: "memory");
      WRITE((kc+1)&1);
      if(kc+2 < nkc) LOAD(kc+2);
    }
    asm volatile("s_waitcnt lgkmcnt(0)" ::: "memory");
    __builtin_amdgcn_s_barrier();
    __builtin_amdgcn_sched_barrier(0);
  }

  #pragma unroll
  for(int s=0;s<2;s++){
    #pragma unroll
    for(int j=0;j<4;j++){
      const int row = blk_row + wv*32 + s*16 + hi*4 + j;
      if(row >= M) continue;
      #pragma unroll
      for(int nf=0;nf<8;nf++){
        const int col = blk_col + nf*16 + lr;
        C[(size_t)row*N + col] = f2bf(acc[s][nf][j]);
      }
    }
  }
}

// ---- fused aggregation v2: half-wave edge pairing ----
// One wave per node. Lanes 0-31 (half 0) accumulate EVEN edges, lanes 32-63
// (half 1) accumulate ODD edges; each lane covers 8 channels (16B) so ONE
// gather instruction fetches TWO source rows. Halves combined at the end via
// one cross-half shuffle. Self-loop term carried by half 0 only.
__global__ __launch_bounds__(256) void k_aggregate(
    const short* __restrict__ h, const float* __restrict__ dinv,
    const int* __restrict__ rowptr, const int* __restrict__ csr_src,
    const float* __restrict__ csr_w, const float* __restrict__ bias,
    short* __restrict__ hout, int nN)
{
  const int wave = threadIdx.x >> 6;
  const int lane = threadIdx.x & 63;
  const int half = lane >> 5;       // 0: even edges, 1: odd edges
  const int hl   = lane & 31;       // channel block: ch hl*8 .. hl*8+7
  const int node = blockIdx.x*4 + wave;
  if(node >= nN) return;
  const float di = dinv[node];
  const int beg = rowptr[node];
  const int deg = rowptr[node+1] - beg;

  // self-loop term (half 0 only; half 1 loads same 16B -> broadcast)
  s8v hv = *(const s8v*)&h[(size_t)node*256 + hl*8];
  const float selfw = (half == 0) ? di*di : 0.f;
  float acc[8];
  #pragma unroll
  for(int q=0;q<8;q++) acc[q] = selfw * b2f(hv[q]);

  for(int base=0; base<deg; base+=64){
    const int cnt = min(deg - base, 64);
    int   myi = (lane < cnt) ? csr_src[beg + base + lane] : 0;
    float myw = (lane < cnt) ? csr_w[beg + base + lane] : 0.f;

    for(int p0=0; p0<cnt; p0+=16){
      s8v v[8]; float w[8]; int s[8];
      #pragma unroll
      for(int t=0;t<8;t++){
        const int e  = p0 + 2*t + half;            // edge index in chunk
        const int sl = (e < cnt) ? e : 0;
        const int   sraw = __shfl(myi, sl);        // uniform-control shfl
        const float wraw = __shfl(myw, sl);
        s[t] = sraw;
        w[t] = (e < cnt) ? wraw : 0.f;
      }
      #pragma unroll
      for(int t=0;t<8;t++)
        v[t] = *(const s8v*)&h[(size_t)s[t]*256 + hl*8];
      #pragma unroll
      for(int t=0;t<8;t++){
        #pragma unroll
        for(int q=0;q<8;q++) acc[q] += w[t] * b2f(v[t][q]);
      }
    }
  }

  // combine halves: lane<32 pulls partner's partial from lane+32
  #pragma unroll
  for(int q=0;q<8;q++){
    float other = __shfl(acc[q], lane | 32);
    acc[q] += (half == 0) ? other : 0.f;
  }

  if(half == 0){
    f4v bv0 = *(const f4v*)&bias[hl*8];
    f4v bv1 = *(const f4v*)&bias[hl*8 + 4];
    s8v ov;
    #pragma unroll
    for(int q=0;q<4;q++){
      ov[q]   = f2bf(fmaxf(acc[q]   + bv0[q], 0.f));
      ov[4+q] = f2bf(fmaxf(acc[4+q] + bv1[q], 0.f));
    }
    *(s8v*)&hout[(size_t)node*256 + hl*8] = ov;
  }
}

// ---- mean-pool: per-(graph,slice) partial sums, no atomics, no memset ----
#define POOL_SPLIT 8
__global__ __launch_bounds__(256) void k_pool(const short* __restrict__ h,
    const int* __restrict__ gstart, float* __restrict__ pool, int nG){
  const int g = blockIdx.x;
  const int sl = blockIdx.y;
  const int c = threadIdx.x;
  const int b = gstart[g], e = gstart[g+1];
  const int len = e - b;
  const int r0 = b + (int)((long long)len * sl / POOL_SPLIT);
  const int r1 = b + (int)((long long)len * (sl+1) / POOL_SPLIT);
  float acc = 0.f;
  for(int r=r0; r<r1; r++) acc += b2f(h[(size_t)r*256 + c]);
  pool[((size_t)g*POOL_SPLIT + sl)*256 + c] = acc;
}

__global__ void k_final(const float* __restrict__ pool, const int* __restrict__ gstart,
                        const float* __restrict__ Wp, const float* __restrict__ bp,
                        float* __restrict__ out, int HID_, int OUT_){
  __shared__ float mean[256];
  int g = blockIdx.x, j = threadIdx.x;
  float c = fmaxf((float)(gstart[g+1] - gstart[g]), 1.0f);
  for(int k=j; k<HID_; k+=blockDim.x){
    float s = 0.f;
    #pragma unroll
    for(int sl=0; sl<POOL_SPLIT; sl++)
      s += pool[((size_t)g*POOL_SPLIT + sl)*HID_ + k];
    mean[k] = s / c;
  }
  __syncthreads();
  float acc = bp[j];
  for(int k=0;k<HID_;k++) acc = fmaf(mean[k], Wp[(size_t)k*OUT_ + j], acc);
  out[(size_t)g*OUT_ + j] = acc;
}

extern "C" void kernel_launch(void* const* d_in, const int* in_sizes, int n_in,
                              void* d_out, int out_size, void* d_ws, size_t ws_size,
                              hipStream_t stream){
  const float* x   = (const float*)d_in[0];
  const int* ei    = (const int*)d_in[1];
  const int* batch = (const int*)d_in[2];
  const float* W1  = (const float*)d_in[3];
  const float* b1  = (const float*)d_in[4];
  const float* W2  = (const float*)d_in[5];
  const float* b2  = (const float*)d_in[6];
  const float* Wp  = (const float*)d_in[7];
  const float* bp  = (const float*)d_in[8];
  float* out = (float*)d_out;

  const int HID    = in_sizes[4];            // 256
  const int IN_DIM = in_sizes[3] / HID;      // 768
  const int OUT    = in_sizes[8];            // 128
  const int nE     = in_sizes[1] / 2;        // 300000
  const int nN     = in_sizes[2];            // 50000
  const int nG     = out_size / OUT;         // 64

  const int* src = ei;
  const int* tgt = ei + nE;

  char* w = (char*)d_ws;
  size_t off = 0;
  auto alloc = [&](size_t bytes)->char*{
    char* p = w + off; off += (bytes + 511) & ~(size_t)511; return p;
  };
  int*   deg     = (int*)  alloc((size_t)nN*4);      // deg+cursor adjacent: one memset
  int*   cursor  = (int*)  alloc((size_t)nN*4);
  float* dinv    = (float*)alloc((size_t)nN*4);
  int*   gstart  = (int*)  alloc((size_t)(nG+1)*4);
  float* pool    = (float*)alloc((size_t)nG*POOL_SPLIT*HID*4);
  int*   rowptr  = (int*)  alloc((size_t)(nN+1)*4);
  int*   csr_src = (int*)  alloc((size_t)nE*4);
  float* csr_w   = (float*)alloc((size_t)nE*4);
  int*   blocksum= (int*)  alloc((size_t)1024*4);
  short* W1T     = (short*)alloc((size_t)IN_DIM*HID*2);
  short* W2T     = (short*)alloc((size_t)HID*HID*2);
  short* h1      = (short*)alloc((size_t)(nN+128)*HID*2);
  short* h2      = (short*)alloc((size_t)(nN+128)*HID*2);
  (void)ws_size; (void)n_in;

  hipMemsetAsync(deg, 0, (size_t)((char*)cursor - (char*)deg) + (size_t)nN*4, stream);

  const int nb = (nN + SCAN_BS - 1) / SCAN_BS;
  k_deg <<<(nE+255)/256, 256, 0, stream>>>(tgt, deg, nE);
  k_scan1_dinv<<<nb, SCAN_BS, 0, stream>>>(deg, rowptr, blocksum, dinv, nN);
  k_scan2_bounds<<<1, 1024, 0, stream>>>(blocksum, nb, batch, gstart, nN, nG);
  k_scan3<<<nb, SCAN_BS, 0, stream>>>(rowptr, blocksum, nN, nE);
  k_fill <<<(nE+255)/256, 256, 0, stream>>>(src, tgt, rowptr, cursor, csr_src, csr_w, dinv, nE);
  k_transpose_cvt2<<<((IN_DIM+HID)*HID+255)/256, 256, 0, stream>>>(W1, W1T, IN_DIM, W2, W2T, HID, HID);

  dim3 gg((nN+127)/128, HID/128);
  const int nagg = (nN + 3) / 4;
  // layer 1 (f32 A, converted in staging regs)
  gemm_stream<true><<<gg, 256, 0, stream>>>(x, W1T, h2, nN, HID, IN_DIM);
  k_aggregate<<<nagg, 256, 0, stream>>>(h2, dinv, rowptr, csr_src, csr_w, b1, h1, nN);
  // layer 2 (bf16 A)
  gemm_stream<false><<<gg, 256, 0, stream>>>(h1, W2T, h2, nN, HID, HID);
  k_aggregate<<<nagg, 256, 0, stream>>>(h2, dinv, rowptr, csr_src, csr_w, b2, h1, nN);
  k_pool<<<dim3(nG, POOL_SPLIT), 256, 0, stream>>>(h1, gstart, pool, nG);
  // head
  k_final<<<nG, OUT, 0, stream>>>(pool, gstart, Wp, bp, out, HID, OUT);
}

// Round 17
// 222.734 us; speedup vs baseline: 1.1658x; 1.1658x over previous
//
#include <hip/hip_runtime.h>
#include <cstdint>
#include <cstddef>

typedef short s8v __attribute__((ext_vector_type(8)));
typedef short s4v __attribute__((ext_vector_type(4)));
typedef float f4v __attribute__((ext_vector_type(4)));

static __device__ __forceinline__ float b2f(short s){
  return __uint_as_float(((uint32_t)(uint16_t)s) << 16);
}
static __device__ __forceinline__ short f2bf(float f){
  uint32_t u = __float_as_uint(f);
  u = (u + 0x7fffu + ((u >> 16) & 1u)) >> 16;
  return (short)(uint16_t)u;
}

// ---- graph prep (fused) ----
__global__ void k_deg(const int* __restrict__ tgt, int* __restrict__ deg, int nE){
  int e = blockIdx.x*blockDim.x + threadIdx.x;
  if(e < nE) atomicAdd(&deg[tgt[e]], 1);
}

#define SCAN_BS 256
__global__ void k_scan1_dinv(const int* __restrict__ deg, int* __restrict__ rowptr,
                             int* __restrict__ blocksum, float* __restrict__ dinv, int nN){
  __shared__ int tmp[SCAN_BS];
  const int t = threadIdx.x;
  const int i = blockIdx.x*SCAN_BS + t;
  int v = (i < nN) ? deg[i] : 0;
  if(i < nN) dinv[i] = rsqrtf((float)v + 1.0f);   // +1 self-loop
  tmp[t] = v; __syncthreads();
  #pragma unroll
  for(int off=1; off<SCAN_BS; off<<=1){
    int x = (t >= off) ? tmp[t-off] : 0;
    __syncthreads();
    tmp[t] += x;
    __syncthreads();
  }
  if(i < nN) rowptr[i] = tmp[t] - v;
  if(t == SCAN_BS-1) blocksum[blockIdx.x] = tmp[t];
}
__global__ void k_scan2_bounds(int* __restrict__ blocksum, int nb,
                               const int* __restrict__ batch, int* __restrict__ gstart,
                               int nN, int nG){
  __shared__ int tmp[1024];
  const int t = threadIdx.x;
  int v = (t < nb) ? blocksum[t] : 0;
  tmp[t] = v; __syncthreads();
  #pragma unroll
  for(int off=1; off<1024; off<<=1){
    int x = (t >= off) ? tmp[t-off] : 0;
    __syncthreads();
    tmp[t] += x;
    __syncthreads();
  }
  if(t < nb) blocksum[t] = tmp[t] - v;
  if(t <= nG){
    int lo = 0, hi = nN;
    while(lo < hi){
      int mid = (lo + hi) >> 1;
      if(batch[mid] < t) lo = mid + 1; else hi = mid;
    }
    gstart[t] = lo;
  }
}
__global__ void k_scan3(int* __restrict__ rowptr, const int* __restrict__ blocksum,
                        int nN, int nE){
  const int i = blockIdx.x*SCAN_BS + threadIdx.x;
  if(i < nN) rowptr[i] += blocksum[blockIdx.x];
  if(i == 0) rowptr[nN] = nE;
}
__global__ void k_fill(const int* __restrict__ src, const int* __restrict__ tgt,
                       const int* __restrict__ rowptr, int* __restrict__ cursor,
                       int* __restrict__ csr_src, float* __restrict__ csr_w,
                       const float* __restrict__ dinv, int nE){
  int e = blockIdx.x*blockDim.x + threadIdx.x;
  if(e >= nE) return;
  int t = tgt[e];
  int s = src[e];
  int pos = rowptr[t] + atomicAdd(&cursor[t], 1);
  csr_src[pos] = s;
  csr_w[pos] = dinv[s] * dinv[t];
}
__global__ void k_transpose_cvt2(const float* __restrict__ W1, short* __restrict__ W1T,
                                 int K1, const float* __restrict__ W2, short* __restrict__ W2T,
                                 int K2, int N){
  int g = blockIdx.x*blockDim.x + threadIdx.x;
  const int t1 = K1*N;
  if(g < t1){
    int n = g / K1, k = g % K1;
    W1T[(size_t)n*K1 + k] = f2bf(W1[(size_t)k*N + n]);
  } else {
    g -= t1;
    if(g >= K2*N) return;
    int n = g / K2, k = g % K2;
    W2T[(size_t)n*K2 + k] = f2bf(W2[(size_t)k*N + n]);
  }
}

// ---- 256x256-tile streaming GEMM (full-N, A read exactly once), T14 reg-staged ----
// C[m][n] = sum_k A[m][k]*Bt[n][k], N == 256. 512 thr (8 waves: 2 row-groups x
// 4 col-groups); per-wave output 128x64 (acc[8][4]). KC=32, NBUF=2.
// Traffic-optimal: 66 MACs per staged byte (2x the 128^2 tile) and grid.y=1
// so A is streamed once. Schedule per iter kc (proven r14): compute(kc) |
// vmcnt(0) [loads(kc+1) landed under compute] | ds_write(kc+1) | issue
// loads(kc+2) (stay in flight across barrier) | lgkmcnt(0) + s_barrier.
// NBUF=2 safety: writes to slot (kc+1)&1 strictly between barrier(kc) and
// barrier(kc+1), where all waves read slot kc&1 only.
template<bool AF32>
__global__ __launch_bounds__(512) void gemm256(const void* __restrict__ Ap,
    const short* __restrict__ Bt, short* __restrict__ C, int M, int N, int K)
{
  __shared__ __align__(16) short As[2][256*32];   // 16 KB per buf
  __shared__ __align__(16) short Bs[2][256*32];   // 16 KB per buf
  const int tid  = threadIdx.x;        // 0..511
  const int lane = tid & 63;
  const int wv   = tid >> 6;           // 0..7
  const int wr   = wv >> 2;            // 0..1  row group (128 rows)
  const int wc   = wv & 3;             // 0..3  col group (64 cols)
  const int lr   = lane & 15;
  const int hi   = lane >> 4;
  const int blk_row = blockIdx.x * 256;
  const int nkc = K / 32;

  const int srow  = tid >> 1;          // staging row/col 0..255
  const int shalf = tid & 1;

  f4v acc[8][4];
  #pragma unroll
  for(int m=0;m<8;m++)
    #pragma unroll
    for(int n=0;n<4;n++){ acc[m][n][0]=0.f; acc[m][n][1]=0.f; acc[m][n][2]=0.f; acc[m][n][3]=0.f; }

  // staging regs
  f4v ar[4];     // A f32: 64B/thread
  s8v ab2[2];    // A bf16: 32B/thread
  s8v br[2];     // B: 32B/thread

  int agrow = blk_row + srow; if(agrow >= M) agrow = M-1;

  auto LOAD = [&](int kc){
    if constexpr(AF32){
      const char* p = (const char*)Ap + ((size_t)agrow*K + (size_t)kc*32)*4 + shalf*64;
      #pragma unroll
      for(int j=0;j<4;j++) ar[j] = *(const f4v*)(p + j*16);
    } else {
      const char* p = (const char*)Ap + ((size_t)agrow*K + (size_t)kc*32)*2 + shalf*32;
      #pragma unroll
      for(int j=0;j<2;j++) ab2[j] = *(const s8v*)(p + j*16);
    }
    const char* q = (const char*)Bt + ((size_t)srow*K + (size_t)kc*32)*2 + shalf*32;
    #pragma unroll
    for(int j=0;j<2;j++) br[j] = *(const s8v*)(q + j*16);
  };
  auto WRITE = [&](int buf){
    const int swz = (srow>>1) & 3;
    if constexpr(AF32){
      #pragma unroll
      for(int u=0;u<2;u++){
        s8v v;
        #pragma unroll
        for(int q=0;q<4;q++){ v[q] = f2bf(ar[2*u][q]); v[4+q] = f2bf(ar[2*u+1][q]); }
        const int pos = (shalf*2 + u) ^ swz;
        *(s8v*)(&As[buf][srow*32 + pos*8]) = v;
      }
    } else {
      #pragma unroll
      for(int u=0;u<2;u++){
        const int pos = (shalf*2 + u) ^ swz;
        *(s8v*)(&As[buf][srow*32 + pos*8]) = ab2[u];
      }
    }
    #pragma unroll
    for(int u=0;u<2;u++){
      const int pos = (shalf*2 + u) ^ swz;
      *(s8v*)(&Bs[buf][srow*32 + pos*8]) = br[u];
    }
  };

  // prologue
  LOAD(0);
  asm volatile("s_waitcnt vmcnt(0)" ::: "memory");
  WRITE(0);
  if(nkc > 1) LOAD(1);
  asm volatile("s_waitcnt lgkmcnt(0)" ::: "memory");
  __builtin_amdgcn_s_barrier();
  __builtin_amdgcn_sched_barrier(0);

  for(int kc=0; kc<nkc; kc++){
    const short* ab = &As[kc&1][0];
    const short* bb = &Bs[kc&1][0];

    s8v b[4];
    #pragma unroll
    for(int n=0;n<4;n++){
      const int row = wc*64 + n*16 + lr;
      const int c = hi ^ ((row>>1) & 3);
      b[n] = *(const s8v*)(bb + row*32 + c*8);
    }
    #pragma unroll
    for(int m=0;m<8;m++){
      const int row = wr*128 + m*16 + lr;
      const int c = hi ^ ((row>>1) & 3);
      s8v a = *(const s8v*)(ab + row*32 + c*8);
      #pragma unroll
      for(int n=0;n<4;n++)
        acc[m][n] = __builtin_amdgcn_mfma_f32_16x16x32_bf16(a, b[n], acc[m][n], 0, 0, 0);
    }

    if(kc+1 < nkc){
      asm volatile("s_waitcnt vmcnt(0)" ::: "memory");   // loads(kc+1) landed under compute
      WRITE((kc+1)&1);
      if(kc+2 < nkc) LOAD(kc+2);                          // in flight across barrier
    }
    asm volatile("s_waitcnt lgkmcnt(0)" ::: "memory");
    __builtin_amdgcn_s_barrier();
    __builtin_amdgcn_sched_barrier(0);
  }

  // epilogue: row = blk_row + wr*128 + m*16 + hi*4 + j, col = wc*64 + n*16 + lr
  #pragma unroll
  for(int m=0;m<8;m++){
    #pragma unroll
    for(int j=0;j<4;j++){
      const int row = blk_row + wr*128 + m*16 + hi*4 + j;
      if(row >= M) continue;
      #pragma unroll
      for(int n=0;n<4;n++){
        const int col = wc*64 + n*16 + lr;
        C[(size_t)row*N + col] = f2bf(acc[m][n][j]);
      }
    }
  }
}

// ---- fused aggregation (v1, proven ~35us): one wave per node, 8-deep gather ----
__global__ __launch_bounds__(256) void k_aggregate(
    const short* __restrict__ h, const float* __restrict__ dinv,
    const int* __restrict__ rowptr, const int* __restrict__ csr_src,
    const float* __restrict__ csr_w, const float* __restrict__ bias,
    short* __restrict__ hout, int nN)
{
  const int wave = threadIdx.x >> 6;
  const int lane = threadIdx.x & 63;
  const int node = blockIdx.x*4 + wave;
  if(node >= nN) return;
  const float di = dinv[node];
  const int beg = rowptr[node];
  const int deg = rowptr[node+1] - beg;

  s4v hv = *(const s4v*)&h[(size_t)node*256 + lane*4];
  const float d2 = di*di;
  f4v acc;
  #pragma unroll
  for(int j=0;j<4;j++) acc[j] = d2 * b2f(hv[j]);

  for(int base=0; base<deg; base+=64){
    const int cnt = min(deg - base, 64);
    int   myi = (lane < cnt) ? csr_src[beg + base + lane] : 0;
    float myw = (lane < cnt) ? csr_w[beg + base + lane] : 0.f;

    for(int p0=0; p0<cnt; p0+=8){
      s4v v[8]; float w[8]; int s[8];
      #pragma unroll
      for(int j=0;j<8;j++){
        int pp = p0 + j;
        int sl = (pp < cnt) ? pp : 0;
        s[j] = __shfl(myi, sl);
        w[j] = (pp < cnt) ? __shfl(myw, sl) : 0.f;
      }
      #pragma unroll
      for(int j=0;j<8;j++)
        v[j] = *(const s4v*)&h[(size_t)s[j]*256 + lane*4];
      #pragma unroll
      for(int j=0;j<8;j++){
        #pragma unroll
        for(int q=0;q<4;q++) acc[q] += w[j] * b2f(v[j][q]);
      }
    }
  }

  f4v bv = *(const f4v*)&bias[lane*4];
  s4v ov;
  #pragma unroll
  for(int j=0;j<4;j++) ov[j] = f2bf(fmaxf(acc[j]+bv[j], 0.f));
  *(s4v*)&hout[(size_t)node*256 + lane*4] = ov;
}

// ---- mean-pool: per-(graph,slice) partial sums, no atomics, no memset ----
#define POOL_SPLIT 8
__global__ __launch_bounds__(256) void k_pool(const short* __restrict__ h,
    const int* __restrict__ gstart, float* __restrict__ pool, int nG){
  const int g = blockIdx.x;
  const int sl = blockIdx.y;
  const int c = threadIdx.x;
  const int b = gstart[g], e = gstart[g+1];
  const int len = e - b;
  const int r0 = b + (int)((long long)len * sl / POOL_SPLIT);
  const int r1 = b + (int)((long long)len * (sl+1) / POOL_SPLIT);
  float acc = 0.f;
  for(int r=r0; r<r1; r++) acc += b2f(h[(size_t)r*256 + c]);
  pool[((size_t)g*POOL_SPLIT + sl)*256 + c] = acc;
}

__global__ void k_final(const float* __restrict__ pool, const int* __restrict__ gstart,
                        const float* __restrict__ Wp, const float* __restrict__ bp,
                        float* __restrict__ out, int HID_, int OUT_){
  __shared__ float mean[256];
  int g = blockIdx.x, j = threadIdx.x;
  float c = fmaxf((float)(gstart[g+1] - gstart[g]), 1.0f);
  for(int k=j; k<HID_; k+=blockDim.x){
    float s = 0.f;
    #pragma unroll
    for(int sl=0; sl<POOL_SPLIT; sl++)
      s += pool[((size_t)g*POOL_SPLIT + sl)*HID_ + k];
    mean[k] = s / c;
  }
  __syncthreads();
  float acc = bp[j];
  for(int k=0;k<HID_;k++) acc = fmaf(mean[k], Wp[(size_t)k*OUT_ + j], acc);
  out[(size_t)g*OUT_ + j] = acc;
}

extern "C" void kernel_launch(void* const* d_in, const int* in_sizes, int n_in,
                              void* d_out, int out_size, void* d_ws, size_t ws_size,
                              hipStream_t stream){
  const float* x   = (const float*)d_in[0];
  const int* ei    = (const int*)d_in[1];
  const int* batch = (const int*)d_in[2];
  const float* W1  = (const float*)d_in[3];
  const float* b1  = (const float*)d_in[4];
  const float* W2  = (const float*)d_in[5];
  const float* b2  = (const float*)d_in[6];
  const float* Wp  = (const float*)d_in[7];
  const float* bp  = (const float*)d_in[8];
  float* out = (float*)d_out;

  const int HID    = in_sizes[4];            // 256
  const int IN_DIM = in_sizes[3] / HID;      // 768
  const int OUT    = in_sizes[8];            // 128
  const int nE     = in_sizes[1] / 2;        // 300000
  const int nN     = in_sizes[2];            // 50000
  const int nG     = out_size / OUT;         // 64

  const int* src = ei;
  const int* tgt = ei + nE;

  char* w = (char*)d_ws;
  size_t off = 0;
  auto alloc = [&](size_t bytes)->char*{
    char* p = w + off; off += (bytes + 511) & ~(size_t)511; return p;
  };
  int*   deg     = (int*)  alloc((size_t)nN*4);      // deg+cursor adjacent: one memset
  int*   cursor  = (int*)  alloc((size_t)nN*4);
  float* dinv    = (float*)alloc((size_t)nN*4);
  int*   gstart  = (int*)  alloc((size_t)(nG+1)*4);
  float* pool    = (float*)alloc((size_t)nG*POOL_SPLIT*HID*4);
  int*   rowptr  = (int*)  alloc((size_t)(nN+1)*4);
  int*   csr_src = (int*)  alloc((size_t)nE*4);
  float* csr_w   = (float*)alloc((size_t)nE*4);
  int*   blocksum= (int*)  alloc((size_t)1024*4);
  short* W1T     = (short*)alloc((size_t)IN_DIM*HID*2);
  short* W2T     = (short*)alloc((size_t)HID*HID*2);
  short* h1      = (short*)alloc((size_t)(nN+256)*HID*2);
  short* h2      = (short*)alloc((size_t)(nN+256)*HID*2);
  (void)ws_size; (void)n_in;

  hipMemsetAsync(deg, 0, (size_t)((char*)cursor - (char*)deg) + (size_t)nN*4, stream);

  const int nb = (nN + SCAN_BS - 1) / SCAN_BS;
  k_deg <<<(nE+255)/256, 256, 0, stream>>>(tgt, deg, nE);
  k_scan1_dinv<<<nb, SCAN_BS, 0, stream>>>(deg, rowptr, blocksum, dinv, nN);
  k_scan2_bounds<<<1, 1024, 0, stream>>>(blocksum, nb, batch, gstart, nN, nG);
  k_scan3<<<nb, SCAN_BS, 0, stream>>>(rowptr, blocksum, nN, nE);
  k_fill <<<(nE+255)/256, 256, 0, stream>>>(src, tgt, rowptr, cursor, csr_src, csr_w, dinv, nE);
  k_transpose_cvt2<<<((IN_DIM+HID)*HID+255)/256, 256, 0, stream>>>(W1, W1T, IN_DIM, W2, W2T, HID, HID);

  const int ngb = (nN + 255) / 256;
  const int nagg = (nN + 3) / 4;
  // layer 1 (f32 A, converted in staging regs; A streamed exactly once)
  gemm256<true><<<ngb, 512, 0, stream>>>(x, W1T, h2, nN, HID, IN_DIM);
  k_aggregate<<<nagg, 256, 0, stream>>>(h2, dinv, rowptr, csr_src, csr_w, b1, h1, nN);
  // layer 2 (bf16 A)
  gemm256<false><<<ngb, 512, 0, stream>>>(h1, W2T, h2, nN, HID, HID);
  k_aggregate<<<nagg, 256, 0, stream>>>(h2, dinv, rowptr, csr_src, csr_w, b2, h1, nN);
  k_pool<<<dim3(nG, POOL_SPLIT), 256, 0, stream>>>(h1, gstart, pool, nG);
  // head
  k_final<<<nG, OUT, 0, stream>>>(pool, gstart, Wp, bp, out, HID, OUT);
}

// Round 18
// 219.989 us; speedup vs baseline: 1.1804x; 1.0125x over previous
//
#include <hip/hip_runtime.h>
#include <cstdint>
#include <cstddef>

typedef short s8v __attribute__((ext_vector_type(8)));
typedef short s4v __attribute__((ext_vector_type(4)));
typedef float f4v __attribute__((ext_vector_type(4)));

static __device__ __forceinline__ float b2f(short s){
  return __uint_as_float(((uint32_t)(uint16_t)s) << 16);
}
static __device__ __forceinline__ short f2bf(float f){
  uint32_t u = __float_as_uint(f);
  u = (u + 0x7fffu + ((u >> 16) & 1u)) >> 16;
  return (short)(uint16_t)u;
}

// ---- merged: edge-degree count + both weight transposes (independent work) ----
__global__ void k_deg_tr(const int* __restrict__ tgt, int* __restrict__ deg, int nE,
                         int degBlocks,
                         const float* __restrict__ W1, short* __restrict__ W1T, int K1,
                         const float* __restrict__ W2, short* __restrict__ W2T, int K2,
                         int N){
  if((int)blockIdx.x < degBlocks){
    int e = blockIdx.x*blockDim.x + threadIdx.x;
    if(e < nE) atomicAdd(&deg[tgt[e]], 1);
  } else {
    int g = (blockIdx.x - degBlocks)*blockDim.x + threadIdx.x;
    const int t1 = K1*N;
    if(g < t1){
      int n = g / K1, k = g % K1;
      W1T[(size_t)n*K1 + k] = f2bf(W1[(size_t)k*N + n]);
    } else {
      g -= t1;
      if(g < K2*N){
        int n = g / K2, k = g % K2;
        W2T[(size_t)n*K2 + k] = f2bf(W2[(size_t)k*N + n]);
      }
    }
  }
}

#define SCAN_BS 256
// block-local exclusive scan of deg -> rowp (in-block); blocksum[b]=block total.
// Also: dinv, and zero cursor (runs before k_fill).
__global__ void k_scan1_dinv(const int* __restrict__ deg, int* __restrict__ rowp,
                             int* __restrict__ blocksum, float* __restrict__ dinv,
                             int* __restrict__ cursor, int nN){
  __shared__ int tmp[SCAN_BS];
  const int t = threadIdx.x;
  const int i = blockIdx.x*SCAN_BS + t;
  int v = (i < nN) ? deg[i] : 0;
  if(i < nN){ dinv[i] = rsqrtf((float)v + 1.0f); cursor[i] = 0; }
  tmp[t] = v; __syncthreads();
  #pragma unroll
  for(int off=1; off<SCAN_BS; off<<=1){
    int x = (t >= off) ? tmp[t-off] : 0;
    __syncthreads();
    tmp[t] += x;
    __syncthreads();
  }
  if(i < nN) rowp[i] = tmp[t] - v;
  if(t == SCAN_BS-1) blocksum[blockIdx.x] = tmp[t];
}
// exclusive scan of blocksums (nb<=1024) + sorted-batch graph bounds
__global__ void k_scan2_bounds(int* __restrict__ blocksum, int nb,
                               const int* __restrict__ batch, int* __restrict__ gstart,
                               int nN, int nG){
  __shared__ int tmp[1024];
  const int t = threadIdx.x;
  int v = (t < nb) ? blocksum[t] : 0;
  tmp[t] = v; __syncthreads();
  #pragma unroll
  for(int off=1; off<1024; off<<=1){
    int x = (t >= off) ? tmp[t-off] : 0;
    __syncthreads();
    tmp[t] += x;
    __syncthreads();
  }
  if(t < nb) blocksum[t] = tmp[t] - v;
  if(t <= nG){
    int lo = 0, hi = nN;
    while(lo < hi){
      int mid = (lo + hi) >> 1;
      if(batch[mid] < t) lo = mid + 1; else hi = mid;
    }
    gstart[t] = lo;
  }
}
// CSR fill; final rowptr reconstructed as rowp[t] + blocksum[t>>8].
// csr entry packed: .x = src index, .y = bit-pattern of edge weight.
__global__ void k_fill(const int* __restrict__ src, const int* __restrict__ tgt,
                       const int* __restrict__ rowp, const int* __restrict__ blocksum,
                       int* __restrict__ cursor, int2* __restrict__ csr,
                       const float* __restrict__ dinv, int nE){
  int e = blockIdx.x*blockDim.x + threadIdx.x;
  if(e >= nE) return;
  int t = tgt[e];
  int s = src[e];
  int pos = rowp[t] + blocksum[t>>8] + atomicAdd(&cursor[t], 1);
  int2 ent;
  ent.x = s;
  ent.y = __float_as_int(dinv[s] * dinv[t]);
  csr[pos] = ent;
}

// ---- 256x256-tile streaming GEMM (full-N, A read exactly once), T14 reg-staged ----
// (r17-verified; see r17 comments for schedule & NBUF=2 safety argument)
template<bool AF32>
__global__ __launch_bounds__(512) void gemm256(const void* __restrict__ Ap,
    const short* __restrict__ Bt, short* __restrict__ C, int M, int N, int K)
{
  __shared__ __align__(16) short As[2][256*32];
  __shared__ __align__(16) short Bs[2][256*32];
  const int tid  = threadIdx.x;
  const int lane = tid & 63;
  const int wv   = tid >> 6;
  const int wr   = wv >> 2;
  const int wc   = wv & 3;
  const int lr   = lane & 15;
  const int hi   = lane >> 4;
  const int blk_row = blockIdx.x * 256;
  const int nkc = K / 32;

  const int srow  = tid >> 1;
  const int shalf = tid & 1;

  f4v acc[8][4];
  #pragma unroll
  for(int m=0;m<8;m++)
    #pragma unroll
    for(int n=0;n<4;n++){ acc[m][n][0]=0.f; acc[m][n][1]=0.f; acc[m][n][2]=0.f; acc[m][n][3]=0.f; }

  f4v ar[4];
  s8v ab2[2];
  s8v br[2];

  int agrow = blk_row + srow; if(agrow >= M) agrow = M-1;

  auto LOAD = [&](int kc){
    if constexpr(AF32){
      const char* p = (const char*)Ap + ((size_t)agrow*K + (size_t)kc*32)*4 + shalf*64;
      #pragma unroll
      for(int j=0;j<4;j++) ar[j] = *(const f4v*)(p + j*16);
    } else {
      const char* p = (const char*)Ap + ((size_t)agrow*K + (size_t)kc*32)*2 + shalf*32;
      #pragma unroll
      for(int j=0;j<2;j++) ab2[j] = *(const s8v*)(p + j*16);
    }
    const char* q = (const char*)Bt + ((size_t)srow*K + (size_t)kc*32)*2 + shalf*32;
    #pragma unroll
    for(int j=0;j<2;j++) br[j] = *(const s8v*)(q + j*16);
  };
  auto WRITE = [&](int buf){
    const int swz = (srow>>1) & 3;
    if constexpr(AF32){
      #pragma unroll
      for(int u=0;u<2;u++){
        s8v v;
        #pragma unroll
        for(int q=0;q<4;q++){ v[q] = f2bf(ar[2*u][q]); v[4+q] = f2bf(ar[2*u+1][q]); }
        const int pos = (shalf*2 + u) ^ swz;
        *(s8v*)(&As[buf][srow*32 + pos*8]) = v;
      }
    } else {
      #pragma unroll
      for(int u=0;u<2;u++){
        const int pos = (shalf*2 + u) ^ swz;
        *(s8v*)(&As[buf][srow*32 + pos*8]) = ab2[u];
      }
    }
    #pragma unroll
    for(int u=0;u<2;u++){
      const int pos = (shalf*2 + u) ^ swz;
      *(s8v*)(&Bs[buf][srow*32 + pos*8]) = br[u];
    }
  };

  LOAD(0);
  asm volatile("s_waitcnt vmcnt(0)" ::: "memory");
  WRITE(0);
  if(nkc > 1) LOAD(1);
  asm volatile("s_waitcnt lgkmcnt(0)" ::: "memory");
  __builtin_amdgcn_s_barrier();
  __builtin_amdgcn_sched_barrier(0);

  for(int kc=0; kc<nkc; kc++){
    const short* ab = &As[kc&1][0];
    const short* bb = &Bs[kc&1][0];

    s8v b[4];
    #pragma unroll
    for(int n=0;n<4;n++){
      const int row = wc*64 + n*16 + lr;
      const int c = hi ^ ((row>>1) & 3);
      b[n] = *(const s8v*)(bb + row*32 + c*8);
    }
    #pragma unroll
    for(int m=0;m<8;m++){
      const int row = wr*128 + m*16 + lr;
      const int c = hi ^ ((row>>1) & 3);
      s8v a = *(const s8v*)(ab + row*32 + c*8);
      #pragma unroll
      for(int n=0;n<4;n++)
        acc[m][n] = __builtin_amdgcn_mfma_f32_16x16x32_bf16(a, b[n], acc[m][n], 0, 0, 0);
    }

    if(kc+1 < nkc){
      asm volatile("s_waitcnt vmcnt(0)" ::: "memory");
      WRITE((kc+1)&1);
      if(kc+2 < nkc) LOAD(kc+2);
    }
    asm volatile("s_waitcnt lgkmcnt(0)" ::: "memory");
    __builtin_amdgcn_s_barrier();
    __builtin_amdgcn_sched_barrier(0);
  }

  #pragma unroll
  for(int m=0;m<8;m++){
    #pragma unroll
    for(int j=0;j<4;j++){
      const int row = blk_row + wr*128 + m*16 + hi*4 + j;
      if(row >= M) continue;
      #pragma unroll
      for(int n=0;n<4;n++){
        const int col = wc*64 + n*16 + lr;
        C[(size_t)row*N + col] = f2bf(acc[m][n][j]);
      }
    }
  }
}

// ---- fused aggregation: one wave per node, packed-int2 CSR, 8-deep gather ----
__global__ __launch_bounds__(256) void k_aggregate(
    const short* __restrict__ h, const float* __restrict__ dinv,
    const int* __restrict__ rowp, const int* __restrict__ blocksum,
    const int2* __restrict__ csr, const float* __restrict__ bias,
    short* __restrict__ hout, int nN, int nE)
{
  const int wave = threadIdx.x >> 6;
  const int lane = threadIdx.x & 63;
  const int node = blockIdx.x*4 + wave;
  if(node >= nN) return;
  const float di = dinv[node];
  const int beg = rowp[node] + blocksum[node>>8];
  const int end = (node+1 < nN) ? (rowp[node+1] + blocksum[(node+1)>>8]) : nE;
  const int deg = end - beg;

  s4v hv = *(const s4v*)&h[(size_t)node*256 + lane*4];
  const float d2 = di*di;
  f4v acc;
  #pragma unroll
  for(int j=0;j<4;j++) acc[j] = d2 * b2f(hv[j]);

  for(int base=0; base<deg; base+=64){
    const int cnt = min(deg - base, 64);
    int myi = 0; float myw = 0.f;
    if(lane < cnt){
      int2 ent = csr[beg + base + lane];
      myi = ent.x;
      myw = __int_as_float(ent.y);
    }

    for(int p0=0; p0<cnt; p0+=8){
      s4v v[8]; float w[8]; int s[8];
      #pragma unroll
      for(int j=0;j<8;j++){
        int pp = p0 + j;
        int sl = (pp < cnt) ? pp : 0;
        s[j] = __shfl(myi, sl);
        w[j] = (pp < cnt) ? __shfl(myw, sl) : 0.f;
      }
      #pragma unroll
      for(int j=0;j<8;j++)
        v[j] = *(const s4v*)&h[(size_t)s[j]*256 + lane*4];
      #pragma unroll
      for(int j=0;j<8;j++){
        #pragma unroll
        for(int q=0;q<4;q++) acc[q] += w[j] * b2f(v[j][q]);
      }
    }
  }

  f4v bv = *(const f4v*)&bias[lane*4];
  s4v ov;
  #pragma unroll
  for(int j=0;j<4;j++) ov[j] = f2bf(fmaxf(acc[j]+bv[j], 0.f));
  *(s4v*)&hout[(size_t)node*256 + lane*4] = ov;
}

// ---- mean-pool: per-(graph,slice) partial sums, no atomics, no memset ----
#define POOL_SPLIT 8
__global__ __launch_bounds__(256) void k_pool(const short* __restrict__ h,
    const int* __restrict__ gstart, float* __restrict__ pool, int nG){
  const int g = blockIdx.x;
  const int sl = blockIdx.y;
  const int c = threadIdx.x;
  const int b = gstart[g], e = gstart[g+1];
  const int len = e - b;
  const int r0 = b + (int)((long long)len * sl / POOL_SPLIT);
  const int r1 = b + (int)((long long)len * (sl+1) / POOL_SPLIT);
  float acc = 0.f;
  for(int r=r0; r<r1; r++) acc += b2f(h[(size_t)r*256 + c]);
  pool[((size_t)g*POOL_SPLIT + sl)*256 + c] = acc;
}

__global__ void k_final(const float* __restrict__ pool, const int* __restrict__ gstart,
                        const float* __restrict__ Wp, const float* __restrict__ bp,
                        float* __restrict__ out, int HID_, int OUT_){
  __shared__ float mean[256];
  int g = blockIdx.x, j = threadIdx.x;
  float c = fmaxf((float)(gstart[g+1] - gstart[g]), 1.0f);
  for(int k=j; k<HID_; k+=blockDim.x){
    float s = 0.f;
    #pragma unroll
    for(int sl=0; sl<POOL_SPLIT; sl++)
      s += pool[((size_t)g*POOL_SPLIT + sl)*HID_ + k];
    mean[k] = s / c;
  }
  __syncthreads();
  float acc = bp[j];
  for(int k=0;k<HID_;k++) acc = fmaf(mean[k], Wp[(size_t)k*OUT_ + j], acc);
  out[(size_t)g*OUT_ + j] = acc;
}

extern "C" void kernel_launch(void* const* d_in, const int* in_sizes, int n_in,
                              void* d_out, int out_size, void* d_ws, size_t ws_size,
                              hipStream_t stream){
  const float* x   = (const float*)d_in[0];
  const int* ei    = (const int*)d_in[1];
  const int* batch = (const int*)d_in[2];
  const float* W1  = (const float*)d_in[3];
  const float* b1  = (const float*)d_in[4];
  const float* W2  = (const float*)d_in[5];
  const float* b2  = (const float*)d_in[6];
  const float* Wp  = (const float*)d_in[7];
  const float* bp  = (const float*)d_in[8];
  float* out = (float*)d_out;

  const int HID    = in_sizes[4];            // 256
  const int IN_DIM = in_sizes[3] / HID;      // 768
  const int OUT    = in_sizes[8];            // 128
  const int nE     = in_sizes[1] / 2;        // 300000
  const int nN     = in_sizes[2];            // 50000
  const int nG     = out_size / OUT;         // 64

  const int* src = ei;
  const int* tgt = ei + nE;

  char* w = (char*)d_ws;
  size_t off = 0;
  auto alloc = [&](size_t bytes)->char*{
    char* p = w + off; off += (bytes + 511) & ~(size_t)511; return p;
  };
  int*   deg     = (int*)  alloc((size_t)nN*4);
  int*   cursor  = (int*)  alloc((size_t)nN*4);
  float* dinv    = (float*)alloc((size_t)nN*4);
  int*   gstart  = (int*)  alloc((size_t)(nG+1)*4);
  float* pool    = (float*)alloc((size_t)nG*POOL_SPLIT*HID*4);
  int*   rowp    = (int*)  alloc((size_t)nN*4);
  int2*  csr     = (int2*) alloc((size_t)nE*8);
  int*   blocksum= (int*)  alloc((size_t)1024*4);
  short* W1T     = (short*)alloc((size_t)IN_DIM*HID*2);
  short* W2T     = (short*)alloc((size_t)HID*HID*2);
  short* h1      = (short*)alloc((size_t)(nN+256)*HID*2);
  short* h2      = (short*)alloc((size_t)(nN+256)*HID*2);
  (void)ws_size; (void)n_in;

  hipMemsetAsync(deg, 0, (size_t)nN*4, stream);

  const int nb = (nN + SCAN_BS - 1) / SCAN_BS;
  const int degBlocks = (nE + 255) / 256;
  const int trBlocks  = ((IN_DIM + HID)*HID + 255) / 256;
  k_deg_tr<<<degBlocks + trBlocks, 256, 0, stream>>>(tgt, deg, nE, degBlocks,
                                                     W1, W1T, IN_DIM, W2, W2T, HID, HID);
  k_scan1_dinv<<<nb, SCAN_BS, 0, stream>>>(deg, rowp, blocksum, dinv, cursor, nN);
  k_scan2_bounds<<<1, 1024, 0, stream>>>(blocksum, nb, batch, gstart, nN, nG);
  k_fill <<<degBlocks, 256, 0, stream>>>(src, tgt, rowp, blocksum, cursor, csr, dinv, nE);

  const int ngb = (nN + 255) / 256;
  const int nagg = (nN + 3) / 4;
  // layer 1 (f32 A, converted in staging regs; A streamed exactly once)
  gemm256<true><<<ngb, 512, 0, stream>>>(x, W1T, h2, nN, HID, IN_DIM);
  k_aggregate<<<nagg, 256, 0, stream>>>(h2, dinv, rowp, blocksum, csr, b1, h1, nN, nE);
  // layer 2 (bf16 A)
  gemm256<false><<<ngb, 512, 0, stream>>>(h1, W2T, h2, nN, HID, HID);
  k_aggregate<<<nagg, 256, 0, stream>>>(h2, dinv, rowp, blocksum, csr, b2, h1, nN, nE);
  k_pool<<<dim3(nG, POOL_SPLIT), 256, 0, stream>>>(h1, gstart, pool, nG);
  // head
  k_final<<<nG, OUT, 0, stream>>>(pool, gstart, Wp, bp, out, HID, OUT);
}